// Round 2
// baseline (465.071 us; speedup 1.0000x reference)
//
#include <hip/hip_runtime.h>
#include <hip/hip_bf16.h>

// SAGEMean3: h = [x | mean_in | mean_out] (50000 x 384), out = relu(h @ W + b)
// R6:
//  - no materialized h: GEMM A-panel staged from xb (kt 0..3) and hagg (kt 4..11),
//    compile-time kt selects the base. Saves 12.8 MB writes + denser L2 panels.
//  - fill/degree: ONE atomic per thread (2E threads) instead of two chained
//    atomics per thread -> halves the per-thread latency chain.
//  - aggregate: 8-deep gather pipeline (8 csr idx loads then 8 row gathers in
//    flight) -> half the latency stalls for deg>=8 (~80% of nodes).

typedef __attribute__((ext_vector_type(8))) short bf16x8;
typedef __attribute__((ext_vector_type(4))) short bf16x4;
typedef __attribute__((ext_vector_type(4))) float f32x4;

#define IN_DIM 128
#define AGG 256
#define K3 384
#define ODIM 1024

static __device__ inline short bfs(float f) {
    union { __hip_bfloat16 b; short s; } u;
    u.b = __float2bfloat16(f);
    return u.s;
}

// fused: [0, wtB) Wt transpose | [wtB, wtB+convB) x->bf16 | rest: degree atomics
__global__ __launch_bounds__(256) void sage_prep(
    const float* __restrict__ x, const int* __restrict__ src,
    const int* __restrict__ dst, const float* __restrict__ W,
    __hip_bfloat16* __restrict__ xb, __hip_bfloat16* __restrict__ Wt,
    int* __restrict__ deg, int n_nodes, int n_edges, int wtB, int convB)
{
    int b = blockIdx.x;
    int t = threadIdx.x;
    if (b < wtB) {
        // Wt[nn][k] = bf16(W[k][nn]); 32x32 tile through LDS
        __shared__ __hip_bfloat16 lds[32][36];
        int tk = b / 32, tn = b % 32;          // 12 x 32 tiles
        int k0 = tk * 32, n0 = tn * 32;
        int r = t >> 3, c = (t & 7) * 4;
        f32x4 w = *(const f32x4*)(W + (size_t)(k0 + r) * ODIM + n0 + c);
#pragma unroll
        for (int i = 0; i < 4; ++i) lds[c + i][r] = __float2bfloat16(w[i]);
        __syncthreads();
        *(bf16x4*)&Wt[(size_t)(n0 + r) * K3 + k0 + c] = *(bf16x4*)&lds[r][c];
        return;
    }
    b -= wtB;
    if (b < convB) {
        int tid = b * 256 + t;                  // over n_nodes*16 (8 elems each)
        if (tid >= n_nodes * 16) return;
        int i = tid >> 4, d8 = (tid & 15) << 3;
        const float* xp = x + (size_t)i * IN_DIM + d8;
        f32x4 a = *(const f32x4*)xp;
        f32x4 c4 = *(const f32x4*)(xp + 4);
        bf16x8 v;
        v[0] = bfs(a.x); v[1] = bfs(a.y); v[2] = bfs(a.z); v[3] = bfs(a.w);
        v[4] = bfs(c4.x); v[5] = bfs(c4.y); v[6] = bfs(c4.z); v[7] = bfs(c4.w);
        *(bf16x8*)(xb + (size_t)i * IN_DIM + d8) = v;
        return;
    }
    b -= convB;
    int e = b * 256 + t;                        // over 2*n_edges, one atomic each
    if (e >= 2 * n_edges) return;
    int idx = (e < n_edges) ? dst[e] : n_nodes + src[e - n_edges];
    atomicAdd(deg + idx, 1);
}

// block-level exclusive scan: 1024 elements per 256-thread block
__global__ __launch_bounds__(256) void scan_partial(
    const int* __restrict__ deg, int* __restrict__ off, int* __restrict__ bsum, int n)
{
    __shared__ int s[256];
    int t = threadIdx.x;
    int base = blockIdx.x * 1024 + t * 4;
    int4 v = {0, 0, 0, 0};
    if (base + 3 < n) v = *(const int4*)(deg + base);
    else {
        if (base     < n) v.x = deg[base];
        if (base + 1 < n) v.y = deg[base + 1];
        if (base + 2 < n) v.z = deg[base + 2];
        if (base + 3 < n) v.w = deg[base + 3];
    }
    int tsum = v.x + v.y + v.z + v.w;
    s[t] = tsum;
    __syncthreads();
#pragma unroll
    for (int d = 1; d < 256; d <<= 1) {
        int add = (t >= d) ? s[t - d] : 0;
        __syncthreads();
        s[t] += add;
        __syncthreads();
    }
    int excl = s[t] - tsum;
    if (t == 255) bsum[blockIdx.x] = s[255];
    int e0 = excl, e1 = e0 + v.x, e2 = e1 + v.y, e3 = e2 + v.z;
    if (base     < n) off[base]     = e0;
    if (base + 1 < n) off[base + 1] = e1;
    if (base + 2 < n) off[base + 2] = e2;
    if (base + 3 < n) off[base + 3] = e3;
}

__global__ __launch_bounds__(256) void scan_bsum(int* __restrict__ bsum, int nblk)
{
    __shared__ int s[256];
    int t = threadIdx.x;
    int v = (t < nblk) ? bsum[t] : 0;
    s[t] = v;
    __syncthreads();
#pragma unroll
    for (int d = 1; d < 256; d <<= 1) {
        int add = (t >= d) ? s[t - d] : 0;
        __syncthreads();
        s[t] += add;
        __syncthreads();
    }
    if (t < nblk) bsum[t] = s[t] - v;   // exclusive
}

// add block offset; also initialize cursor = off (for fill)
__global__ __launch_bounds__(256) void scan_add(
    int* __restrict__ off, int* __restrict__ cursor,
    const int* __restrict__ bsum, int n)
{
    int base = blockIdx.x * 1024 + threadIdx.x * 4;
    int b = bsum[blockIdx.x];
#pragma unroll
    for (int j = 0; j < 4; ++j)
        if (base + j < n) {
            int v = off[base + j] + b;
            off[base + j]    = v;
            cursor[base + j] = v;
        }
}

// one atomic + one scattered store per thread (2E threads)
__global__ __launch_bounds__(256) void sage_fill(
    const int* __restrict__ src, const int* __restrict__ dst,
    int* __restrict__ cursor, int* __restrict__ csr, int n_nodes, int n_edges)
{
    int t = blockIdx.x * 256 + threadIdx.x;
    if (t >= 2 * n_edges) return;
    int node, val;
    if (t < n_edges) { node = dst[t]; val = src[t]; }                 // in-list of dst
    else { int e = t - n_edges; node = n_nodes + src[e]; val = dst[e]; } // out-list of src
    int p = atomicAdd(cursor + node, 1);
    csr[p] = val;
}

// one wave per (node, direction): bf16 gathers, fp32 accumulate, 8-deep pipeline
__global__ __launch_bounds__(256) void sage_aggregate(
    const __hip_bfloat16* __restrict__ xb, const int* __restrict__ csr,
    const int* __restrict__ off, const int* __restrict__ deg,
    __hip_bfloat16* __restrict__ hagg, int n_nodes)
{
    int wid  = (int)((blockIdx.x * 256 + threadIdx.x) >> 6);
    int lane = threadIdx.x & 63;
    if (wid >= 2 * n_nodes) return;
    int i = wid >> 1;
    int d = wid & 1;
    int idx = i + d * n_nodes;

    float2 a = {0.f, 0.f};
    int b0 = off[idx], dg = deg[idx];
    const int* cp = csr + b0;

#define GATHER(nb) { \
    __hip_bfloat162 v = ((const __hip_bfloat162*)(xb + (size_t)(nb) * IN_DIM))[lane]; \
    a.x += __low2float(v); a.y += __high2float(v); }

    int e = 0;
    for (; e + 7 < dg; e += 8) {
        int a0 = cp[e],     a1 = cp[e + 1], a2 = cp[e + 2], a3 = cp[e + 3];
        int a4 = cp[e + 4], a5 = cp[e + 5], a6 = cp[e + 6], a7 = cp[e + 7];
        GATHER(a0) GATHER(a1) GATHER(a2) GATHER(a3)
        GATHER(a4) GATHER(a5) GATHER(a6) GATHER(a7)
    }
    for (; e + 3 < dg; e += 4) {
        int a0 = cp[e], a1 = cp[e + 1], a2 = cp[e + 2], a3 = cp[e + 3];
        GATHER(a0) GATHER(a1) GATHER(a2) GATHER(a3)
    }
    for (; e < dg; ++e) { int a0 = cp[e]; GATHER(a0) }
#undef GATHER

    float inv = 1.0f / (float)max(dg, 1);
    __hip_bfloat162 p;
    p.x = __float2bfloat16(a.x * inv);
    p.y = __float2bfloat16(a.y * inv);
    ((__hip_bfloat162*)(hagg + (size_t)i * AGG))[(d << 6) + lane] = p;
}

// 128x128 block tile, 2x2 waves of 64x64, BK=32, double-buffered LDS staging.
// A-panel staged from xb (kt 0..3, row stride 128) and hagg (kt 4..11, row
// stride 256); base chosen at compile-time kt. LDS slot seg of row r holds
// global kseg seg^(r&3).
__global__ __launch_bounds__(256, 4) void sage_gemm(
    const __hip_bfloat16* __restrict__ xb, const __hip_bfloat16* __restrict__ hagg,
    const __hip_bfloat16* __restrict__ Wt, const float* __restrict__ bias,
    float* __restrict__ out, int n_nodes)
{
    __shared__ __hip_bfloat16 Asm[2][128 * 32];   // 2 x 8 KB
    __shared__ __hip_bfloat16 Bsm[2][128 * 32];   // 2 x 8 KB

    int t    = threadIdx.x;
    int wave = t >> 6;
    int lane = t & 63;

    // bijective XCD swizzle: same-tm blocks land on one XCD's L2 (grid % 8 == 0)
    int bid = blockIdx.x;
    int sid = bid;
    if ((gridDim.x & 7) == 0) {
        int cpx = gridDim.x >> 3;
        sid = (bid & 7) * cpx + (bid >> 3);
    }
    int tn   = sid & 7;       // 8 n-tiles of 128
    int tm   = sid >> 3;      // m-tiles of 128
    int m0   = tm * 128;
    int n0   = tn * 128;
    int wm   = wave >> 1;
    int wn   = wave & 1;
    int m    = lane & 15;
    int quad = lane >> 4;

    // per-thread staging addresses: chunks t and t+256 (rows r, r+64; same seg)
    int srow = t >> 2;
    int seg  = t & 3;
    int g    = seg ^ (srow & 3);     // (srow+64)&3 == srow&3
    int ga0  = m0 + srow;       if (ga0 >= n_nodes) ga0 = n_nodes - 1;
    int ga1  = m0 + srow + 64;  if (ga1 >= n_nodes) ga1 = n_nodes - 1;
    const __hip_bfloat16* xA0 = xb   + (size_t)ga0 * IN_DIM + g * 8;
    const __hip_bfloat16* xA1 = xb   + (size_t)ga1 * IN_DIM + g * 8;
    const __hip_bfloat16* hA0 = hagg + (size_t)ga0 * AGG    + g * 8;
    const __hip_bfloat16* hA1 = hagg + (size_t)ga1 * AGG    + g * 8;
    const __hip_bfloat16* gB0 = Wt + (size_t)(n0 + srow) * K3 + g * 8;
    const __hip_bfloat16* gB1 = Wt + (size_t)(n0 + srow + 64) * K3 + g * 8;
    // wave-uniform LDS bases (+ lane*16 implicit)
    int l0 = (0 * 256 + wave * 64) * 8;
    int l1 = (1 * 256 + wave * 64) * 8;

    f32x4 acc[4][4];
#pragma unroll
    for (int s = 0; s < 4; ++s)
#pragma unroll
        for (int u = 0; u < 4; ++u) acc[s][u] = (f32x4){0.f, 0.f, 0.f, 0.f};

    // prologue: stage ktile 0 into buffer 0 (kt=0 -> xb source)
    __builtin_amdgcn_global_load_lds(xA0, &Asm[0][l0], 16, 0, 0);
    __builtin_amdgcn_global_load_lds(xA1, &Asm[0][l1], 16, 0, 0);
    __builtin_amdgcn_global_load_lds(gB0, &Bsm[0][l0], 16, 0, 0);
    __builtin_amdgcn_global_load_lds(gB1, &Bsm[0][l1], 16, 0, 0);

    int slot = quad ^ (m & 3);
#pragma unroll
    for (int kt = 0; kt < 12; ++kt) {
        int p = kt & 1;
        __syncthreads();   // drains stage(kt) [in flight for one full compute] + prior reads
        if (kt < 11) {     // stage kt+1 into the other buffer, overlapped with compute
            int kn = kt + 1;  // literal after unroll -> base select folds
            const __hip_bfloat16* pA0 = (kn < 4) ? xA0 + kn * 32 : hA0 + (kn - 4) * 32;
            const __hip_bfloat16* pA1 = (kn < 4) ? xA1 + kn * 32 : hA1 + (kn - 4) * 32;
            __builtin_amdgcn_global_load_lds(pA0, &Asm[p ^ 1][l0], 16, 0, 0);
            __builtin_amdgcn_global_load_lds(pA1, &Asm[p ^ 1][l1], 16, 0, 0);
            __builtin_amdgcn_global_load_lds(gB0 + kn * 32, &Bsm[p ^ 1][l0], 16, 0, 0);
            __builtin_amdgcn_global_load_lds(gB1 + kn * 32, &Bsm[p ^ 1][l1], 16, 0, 0);
        }
        bf16x8 a[4], b[4];
#pragma unroll
        for (int s = 0; s < 4; ++s) {
            int row = wm * 64 + s * 16 + m;
            a[s] = *(const bf16x8*)&Asm[p][row * 32 + slot * 8];
        }
#pragma unroll
        for (int u = 0; u < 4; ++u) {
            int row = wn * 64 + u * 16 + m;
            b[u] = *(const bf16x8*)&Bsm[p][row * 32 + slot * 8];
        }
#pragma unroll
        for (int s = 0; s < 4; ++s)
#pragma unroll
            for (int u = 0; u < 4; ++u)
                acc[s][u] = __builtin_amdgcn_mfma_f32_16x16x32_bf16(a[s], b[u], acc[s][u], 0, 0, 0);
    }

    // epilogue: u innermost so the two 64B halves of each 128B line are written
    // back-to-back; nontemporal so the 205MB out stream doesn't evict xb/hagg/Wt in L2.
    float bv[4];
#pragma unroll
    for (int u = 0; u < 4; ++u) bv[u] = bias[n0 + wn * 64 + u * 16 + m];

    bool full = (m0 + 128 <= n_nodes);   // uniform per block
    if (full) {
#pragma unroll
        for (int s = 0; s < 4; ++s) {
            int r0 = m0 + wm * 64 + s * 16 + quad * 4;
#pragma unroll
            for (int r = 0; r < 4; ++r) {
                float* orow = out + (size_t)(r0 + r) * ODIM + n0 + wn * 64 + m;
#pragma unroll
                for (int u = 0; u < 4; ++u)
                    __builtin_nontemporal_store(fmaxf(acc[s][u][r] + bv[u], 0.f), orow + u * 16);
            }
        }
    } else {
#pragma unroll
        for (int s = 0; s < 4; ++s) {
            int r0 = m0 + wm * 64 + s * 16 + quad * 4;
#pragma unroll
            for (int r = 0; r < 4; ++r) {
                if (r0 + r >= n_nodes) continue;
                float* orow = out + (size_t)(r0 + r) * ODIM + n0 + wn * 64 + m;
#pragma unroll
                for (int u = 0; u < 4; ++u)
                    __builtin_nontemporal_store(fmaxf(acc[s][u][r] + bv[u], 0.f), orow + u * 16);
            }
        }
    }
}

extern "C" void kernel_launch(void* const* d_in, const int* in_sizes, int n_in,
                              void* d_out, int out_size, void* d_ws, size_t ws_size,
                              hipStream_t stream)
{
    const float* x    = (const float*)d_in[0];
    const int*   ei   = (const int*)d_in[1];
    const float* W    = (const float*)d_in[2];
    const float* bias = (const float*)d_in[3];

    int n_nodes = in_sizes[0] / IN_DIM;
    int n_edges = in_sizes[1] / 2;
    const int* src = ei;
    const int* dst = ei + n_edges;
    int n2 = 2 * n_nodes;

    // ws layout: deg[2N] | cursor[2N] | off[2N] | bsum[256] | csr[2E] | hagg | Wt | xb
    char* ws = (char*)d_ws;
    int* deg    = (int*)ws;
    int* cursor = deg + n2;
    int* off    = cursor + n2;
    int* bsum   = off + n2;
    int* csr    = bsum + 256;
    __hip_bfloat16* hagg = (__hip_bfloat16*)(csr + 2 * n_edges);
    __hip_bfloat16* Wt   = hagg + (size_t)n_nodes * AGG;
    __hip_bfloat16* xb   = Wt + (size_t)K3 * ODIM;

    hipMemsetAsync(deg, 0, (size_t)n2 * sizeof(int), stream);

    int wtB   = (K3 / 32) * (ODIM / 32);             // 384
    int convB = (n_nodes * 16 + 255) / 256;          // 3125
    int degB  = (2 * n_edges + 255) / 256;           // 4688
    sage_prep<<<wtB + convB + degB, 256, 0, stream>>>(
        x, src, dst, W, xb, Wt, deg, n_nodes, n_edges, wtB, convB);

    int nblk = (n2 + 1023) / 1024;   // 98 for N=50000
    scan_partial<<<nblk, 256, 0, stream>>>(deg, off, bsum, n2);
    scan_bsum<<<1, 256, 0, stream>>>(bsum, nblk);
    scan_add<<<nblk, 256, 0, stream>>>(off, cursor, bsum, n2);

    sage_fill<<<degB, 256, 0, stream>>>(src, dst, cursor, csr, n_nodes, n_edges);

    sage_aggregate<<<(n2 + 3) / 4, 256, 0, stream>>>(xb, csr, off, deg, hagg, n_nodes);

    int tiles_m = (n_nodes + 127) / 128;         // 391
    int blocks  = tiles_m * (ODIM / 128);        // 3128
    sage_gemm<<<blocks, 256, 0, stream>>>(xb, hagg, Wt, bias, (float*)d_out, n_nodes);
}

// Round 3
// 397.704 us; speedup vs baseline: 1.1694x; 1.1694x over previous
//
#include <hip/hip_runtime.h>
#include <hip/hip_bf16.h>

// SAGEMean3: h = [x | mean_in | mean_out] (50000 x 384), out = relu(h @ W + b)
// R7:
//  - degree pass RETURNS slot: pos[e] = atomicAdd(deg+idx,1). sage_fill is now
//    atomic-free pure streaming (csr[off[idx]+pos[e]] = val) -> removes the
//    second 1.2M-deep atomic-with-return latency chain.
//  - aggregate: 4 rows per gather instr (16 lanes x 16B, quad q = row e+q),
//    cross-quad shfl_xor reduce -> 4x fewer VMEM gather instructions.
//  - scan_bsum merged into scan_add (each block rescans the 98 bsums in LDS).
//  - GEMM unchanged: xb/hagg split A-panel, XCD swizzle, nontemporal epilogue.

typedef __attribute__((ext_vector_type(8))) short bf16x8;
typedef __attribute__((ext_vector_type(4))) short bf16x4;
typedef __attribute__((ext_vector_type(4))) float f32x4;

#define IN_DIM 128
#define AGG 256
#define K3 384
#define ODIM 1024

static __device__ inline short bfs(float f) {
    union { __hip_bfloat16 b; short s; } u;
    u.b = __float2bfloat16(f);
    return u.s;
}

static __device__ inline float bf2f(short s) {
    union { unsigned u; float f; } c;
    c.u = ((unsigned)(unsigned short)s) << 16;
    return c.f;
}

// fused: [0, wtB) Wt transpose | [wtB, wtB+convB) x->bf16 | rest: degree+pos
__global__ __launch_bounds__(256) void sage_prep(
    const float* __restrict__ x, const int* __restrict__ src,
    const int* __restrict__ dst, const float* __restrict__ W,
    __hip_bfloat16* __restrict__ xb, __hip_bfloat16* __restrict__ Wt,
    int* __restrict__ deg, int* __restrict__ pos,
    int n_nodes, int n_edges, int wtB, int convB)
{
    int b = blockIdx.x;
    int t = threadIdx.x;
    if (b < wtB) {
        // Wt[nn][k] = bf16(W[k][nn]); 32x32 tile through LDS
        __shared__ __hip_bfloat16 lds[32][36];
        int tk = b / 32, tn = b % 32;          // 12 x 32 tiles
        int k0 = tk * 32, n0 = tn * 32;
        int r = t >> 3, c = (t & 7) * 4;
        f32x4 w = *(const f32x4*)(W + (size_t)(k0 + r) * ODIM + n0 + c);
#pragma unroll
        for (int i = 0; i < 4; ++i) lds[c + i][r] = __float2bfloat16(w[i]);
        __syncthreads();
        *(bf16x4*)&Wt[(size_t)(n0 + r) * K3 + k0 + c] = *(bf16x4*)&lds[r][c];
        return;
    }
    b -= wtB;
    if (b < convB) {
        int tid = b * 256 + t;                  // over n_nodes*16 (8 elems each)
        if (tid >= n_nodes * 16) return;
        int i = tid >> 4, d8 = (tid & 15) << 3;
        const float* xp = x + (size_t)i * IN_DIM + d8;
        f32x4 a = *(const f32x4*)xp;
        f32x4 c4 = *(const f32x4*)(xp + 4);
        bf16x8 v;
        v[0] = bfs(a.x); v[1] = bfs(a.y); v[2] = bfs(a.z); v[3] = bfs(a.w);
        v[4] = bfs(c4.x); v[5] = bfs(c4.y); v[6] = bfs(c4.z); v[7] = bfs(c4.w);
        *(bf16x8*)(xb + (size_t)i * IN_DIM + d8) = v;
        return;
    }
    b -= convB;
    int e = b * 256 + t;                        // over 2*n_edges
    if (e >= 2 * n_edges) return;
    int idx = (e < n_edges) ? dst[e] : n_nodes + src[e - n_edges];
    pos[e] = atomicAdd(deg + idx, 1);
}

// block-level exclusive scan: 1024 elements per 256-thread block
__global__ __launch_bounds__(256) void scan_partial(
    const int* __restrict__ deg, int* __restrict__ off, int* __restrict__ bsum, int n)
{
    __shared__ int s[256];
    int t = threadIdx.x;
    int base = blockIdx.x * 1024 + t * 4;
    int4 v = {0, 0, 0, 0};
    if (base + 3 < n) v = *(const int4*)(deg + base);
    else {
        if (base     < n) v.x = deg[base];
        if (base + 1 < n) v.y = deg[base + 1];
        if (base + 2 < n) v.z = deg[base + 2];
        if (base + 3 < n) v.w = deg[base + 3];
    }
    int tsum = v.x + v.y + v.z + v.w;
    s[t] = tsum;
    __syncthreads();
#pragma unroll
    for (int d = 1; d < 256; d <<= 1) {
        int add = (t >= d) ? s[t - d] : 0;
        __syncthreads();
        s[t] += add;
        __syncthreads();
    }
    int excl = s[t] - tsum;
    if (t == 255) bsum[blockIdx.x] = s[255];
    int e0 = excl, e1 = e0 + v.x, e2 = e1 + v.y, e3 = e2 + v.z;
    if (base     < n) off[base]     = e0;
    if (base + 1 < n) off[base + 1] = e1;
    if (base + 2 < n) off[base + 2] = e2;
    if (base + 3 < n) off[base + 3] = e3;
}

// each block rescans bsum in LDS, adds its exclusive block offset
__global__ __launch_bounds__(256) void scan_add(
    int* __restrict__ off, const int* __restrict__ bsum, int n, int nblk)
{
    __shared__ int s[256];
    int t = threadIdx.x;
    int v = (t < nblk) ? bsum[t] : 0;
    s[t] = v;
    __syncthreads();
#pragma unroll
    for (int d = 1; d < 256; d <<= 1) {
        int add = (t >= d) ? s[t - d] : 0;
        __syncthreads();
        s[t] += add;
        __syncthreads();
    }
    int b = s[blockIdx.x] - ((blockIdx.x < nblk) ? bsum[blockIdx.x] : 0);
    int base = blockIdx.x * 1024 + t * 4;
#pragma unroll
    for (int j = 0; j < 4; ++j)
        if (base + j < n) off[base + j] += b;
}

// atomic-free: slot was captured in the degree pass
__global__ __launch_bounds__(256) void sage_fill(
    const int* __restrict__ src, const int* __restrict__ dst,
    const int* __restrict__ off, const int* __restrict__ pos,
    int* __restrict__ csr, int n_nodes, int n_edges)
{
    int t = blockIdx.x * 256 + threadIdx.x;
    if (t >= 2 * n_edges) return;
    int node, val;
    if (t < n_edges) { node = dst[t]; val = src[t]; }                    // in-list of dst
    else { int e = t - n_edges; node = n_nodes + src[e]; val = dst[e]; } // out-list of src
    csr[off[node] + pos[t]] = val;
}

// one wave per (node, direction): 4 rows per gather instr, cross-quad reduce
__global__ __launch_bounds__(256) void sage_aggregate(
    const __hip_bfloat16* __restrict__ xb, const int* __restrict__ csr,
    const int* __restrict__ off, const int* __restrict__ deg,
    __hip_bfloat16* __restrict__ hagg, int n_nodes)
{
    int wid  = (int)((blockIdx.x * 256 + threadIdx.x) >> 6);
    int lane = threadIdx.x & 63;
    if (wid >= 2 * n_nodes) return;
    int i = wid >> 1;
    int d = wid & 1;
    int idx = i + d * n_nodes;

    int b0 = off[idx], dg = deg[idx];
    const int* cp = csr + b0;
    int q = lane >> 4, sub = lane & 15;

    float acc[8];
#pragma unroll
    for (int j = 0; j < 8; ++j) acc[j] = 0.f;

#define ACC8(v) { _Pragma("unroll") \
    for (int j = 0; j < 8; ++j) acc[j] += bf2f((v)[j]); }

    // quad q gathers row cp[e+q]: 4 rows per instruction, unroll 2 -> 8 in flight
    int e = 0;
    for (; e + 7 < dg; e += 8) {
        int r0 = cp[e + q];
        int r1 = cp[e + 4 + q];
        bf16x8 v0 = *(const bf16x8*)(xb + (size_t)r0 * IN_DIM + sub * 8);
        bf16x8 v1 = *(const bf16x8*)(xb + (size_t)r1 * IN_DIM + sub * 8);
        ACC8(v0) ACC8(v1)
    }
    for (; e < dg; e += 4) {
        int eq = e + q;
        int rq = cp[min(eq, dg - 1)];            // clamp: always in-bounds
        bf16x8 v = *(const bf16x8*)(xb + (size_t)rq * IN_DIM + sub * 8);
        if (eq < dg) ACC8(v)
    }
#undef ACC8

    // sum the 4 quads: lanes {sub, sub+16, sub+32, sub+48} hold disjoint subsets
#pragma unroll
    for (int j = 0; j < 8; ++j) {
        acc[j] += __shfl_xor(acc[j], 16);
        acc[j] += __shfl_xor(acc[j], 32);
    }

    float inv = 1.0f / (float)max(dg, 1);
    if (q == 0) {
        bf16x8 o;
#pragma unroll
        for (int j = 0; j < 8; ++j) o[j] = bfs(acc[j] * inv);
        *(bf16x8*)(hagg + (size_t)i * AGG + d * IN_DIM + sub * 8) = o;
    }
}

// 128x128 block tile, 2x2 waves of 64x64, BK=32, double-buffered LDS staging.
// A-panel staged from xb (kt 0..3, row stride 128) and hagg (kt 4..11, row
// stride 256); base chosen at compile-time kt. LDS slot seg of row r holds
// global kseg seg^(r&3).
__global__ __launch_bounds__(256, 4) void sage_gemm(
    const __hip_bfloat16* __restrict__ xb, const __hip_bfloat16* __restrict__ hagg,
    const __hip_bfloat16* __restrict__ Wt, const float* __restrict__ bias,
    float* __restrict__ out, int n_nodes)
{
    __shared__ __hip_bfloat16 Asm[2][128 * 32];   // 2 x 8 KB
    __shared__ __hip_bfloat16 Bsm[2][128 * 32];   // 2 x 8 KB

    int t    = threadIdx.x;
    int wave = t >> 6;
    int lane = t & 63;

    // bijective XCD swizzle: same-tm blocks land on one XCD's L2 (grid % 8 == 0)
    int bid = blockIdx.x;
    int sid = bid;
    if ((gridDim.x & 7) == 0) {
        int cpx = gridDim.x >> 3;
        sid = (bid & 7) * cpx + (bid >> 3);
    }
    int tn   = sid & 7;       // 8 n-tiles of 128
    int tm   = sid >> 3;      // m-tiles of 128
    int m0   = tm * 128;
    int n0   = tn * 128;
    int wm   = wave >> 1;
    int wn   = wave & 1;
    int m    = lane & 15;
    int quad = lane >> 4;

    // per-thread staging addresses: chunks t and t+256 (rows r, r+64; same seg)
    int srow = t >> 2;
    int seg  = t & 3;
    int g    = seg ^ (srow & 3);     // (srow+64)&3 == srow&3
    int ga0  = m0 + srow;       if (ga0 >= n_nodes) ga0 = n_nodes - 1;
    int ga1  = m0 + srow + 64;  if (ga1 >= n_nodes) ga1 = n_nodes - 1;
    const __hip_bfloat16* xA0 = xb   + (size_t)ga0 * IN_DIM + g * 8;
    const __hip_bfloat16* xA1 = xb   + (size_t)ga1 * IN_DIM + g * 8;
    const __hip_bfloat16* hA0 = hagg + (size_t)ga0 * AGG    + g * 8;
    const __hip_bfloat16* hA1 = hagg + (size_t)ga1 * AGG    + g * 8;
    const __hip_bfloat16* gB0 = Wt + (size_t)(n0 + srow) * K3 + g * 8;
    const __hip_bfloat16* gB1 = Wt + (size_t)(n0 + srow + 64) * K3 + g * 8;
    // wave-uniform LDS bases (+ lane*16 implicit)
    int l0 = (0 * 256 + wave * 64) * 8;
    int l1 = (1 * 256 + wave * 64) * 8;

    f32x4 acc[4][4];
#pragma unroll
    for (int s = 0; s < 4; ++s)
#pragma unroll
        for (int u = 0; u < 4; ++u) acc[s][u] = (f32x4){0.f, 0.f, 0.f, 0.f};

    // prologue: stage ktile 0 into buffer 0 (kt=0 -> xb source)
    __builtin_amdgcn_global_load_lds(xA0, &Asm[0][l0], 16, 0, 0);
    __builtin_amdgcn_global_load_lds(xA1, &Asm[0][l1], 16, 0, 0);
    __builtin_amdgcn_global_load_lds(gB0, &Bsm[0][l0], 16, 0, 0);
    __builtin_amdgcn_global_load_lds(gB1, &Bsm[0][l1], 16, 0, 0);

    int slot = quad ^ (m & 3);
#pragma unroll
    for (int kt = 0; kt < 12; ++kt) {
        int p = kt & 1;
        __syncthreads();   // drains stage(kt) [in flight for one full compute] + prior reads
        if (kt < 11) {     // stage kt+1 into the other buffer, overlapped with compute
            int kn = kt + 1;  // literal after unroll -> base select folds
            const __hip_bfloat16* pA0 = (kn < 4) ? xA0 + kn * 32 : hA0 + (kn - 4) * 32;
            const __hip_bfloat16* pA1 = (kn < 4) ? xA1 + kn * 32 : hA1 + (kn - 4) * 32;
            __builtin_amdgcn_global_load_lds(pA0, &Asm[p ^ 1][l0], 16, 0, 0);
            __builtin_amdgcn_global_load_lds(pA1, &Asm[p ^ 1][l1], 16, 0, 0);
            __builtin_amdgcn_global_load_lds(gB0 + kn * 32, &Bsm[p ^ 1][l0], 16, 0, 0);
            __builtin_amdgcn_global_load_lds(gB1 + kn * 32, &Bsm[p ^ 1][l1], 16, 0, 0);
        }
        bf16x8 a[4], b[4];
#pragma unroll
        for (int s = 0; s < 4; ++s) {
            int row = wm * 64 + s * 16 + m;
            a[s] = *(const bf16x8*)&Asm[p][row * 32 + slot * 8];
        }
#pragma unroll
        for (int u = 0; u < 4; ++u) {
            int row = wn * 64 + u * 16 + m;
            b[u] = *(const bf16x8*)&Bsm[p][row * 32 + slot * 8];
        }
#pragma unroll
        for (int s = 0; s < 4; ++s)
#pragma unroll
            for (int u = 0; u < 4; ++u)
                acc[s][u] = __builtin_amdgcn_mfma_f32_16x16x32_bf16(a[s], b[u], acc[s][u], 0, 0, 0);
    }

    // epilogue: u innermost so the two 64B halves of each 128B line are written
    // back-to-back; nontemporal so the 205MB out stream doesn't evict xb/hagg/Wt in L2.
    float bv[4];
#pragma unroll
    for (int u = 0; u < 4; ++u) bv[u] = bias[n0 + wn * 64 + u * 16 + m];

    bool full = (m0 + 128 <= n_nodes);   // uniform per block
    if (full) {
#pragma unroll
        for (int s = 0; s < 4; ++s) {
            int r0 = m0 + wm * 64 + s * 16 + quad * 4;
#pragma unroll
            for (int r = 0; r < 4; ++r) {
                float* orow = out + (size_t)(r0 + r) * ODIM + n0 + wn * 64 + m;
#pragma unroll
                for (int u = 0; u < 4; ++u)
                    __builtin_nontemporal_store(fmaxf(acc[s][u][r] + bv[u], 0.f), orow + u * 16);
            }
        }
    } else {
#pragma unroll
        for (int s = 0; s < 4; ++s) {
            int r0 = m0 + wm * 64 + s * 16 + quad * 4;
#pragma unroll
            for (int r = 0; r < 4; ++r) {
                if (r0 + r >= n_nodes) continue;
                float* orow = out + (size_t)(r0 + r) * ODIM + n0 + wn * 64 + m;
#pragma unroll
                for (int u = 0; u < 4; ++u)
                    __builtin_nontemporal_store(fmaxf(acc[s][u][r] + bv[u], 0.f), orow + u * 16);
            }
        }
    }
}

extern "C" void kernel_launch(void* const* d_in, const int* in_sizes, int n_in,
                              void* d_out, int out_size, void* d_ws, size_t ws_size,
                              hipStream_t stream)
{
    const float* x    = (const float*)d_in[0];
    const int*   ei   = (const int*)d_in[1];
    const float* W    = (const float*)d_in[2];
    const float* bias = (const float*)d_in[3];

    int n_nodes = in_sizes[0] / IN_DIM;
    int n_edges = in_sizes[1] / 2;
    const int* src = ei;
    const int* dst = ei + n_edges;
    int n2 = 2 * n_nodes;

    // ws layout: deg[2N] | off[2N] | bsum[256] | pos[2E] | csr[2E] | hagg | Wt | xb
    char* ws = (char*)d_ws;
    int* deg  = (int*)ws;
    int* off  = deg + n2;
    int* bsum = off + n2;
    int* pos  = bsum + 256;
    int* csr  = pos + 2 * n_edges;
    __hip_bfloat16* hagg = (__hip_bfloat16*)(csr + 2 * n_edges);
    __hip_bfloat16* Wt   = hagg + (size_t)n_nodes * AGG;
    __hip_bfloat16* xb   = Wt + (size_t)K3 * ODIM;

    hipMemsetAsync(deg, 0, (size_t)n2 * sizeof(int), stream);

    int wtB   = (K3 / 32) * (ODIM / 32);             // 384
    int convB = (n_nodes * 16 + 255) / 256;          // 3125
    int degB  = (2 * n_edges + 255) / 256;           // 4688
    sage_prep<<<wtB + convB + degB, 256, 0, stream>>>(
        x, src, dst, W, xb, Wt, deg, pos, n_nodes, n_edges, wtB, convB);

    int nblk = (n2 + 1023) / 1024;   // 98 for N=50000
    scan_partial<<<nblk, 256, 0, stream>>>(deg, off, bsum, n2);
    scan_add<<<nblk, 256, 0, stream>>>(off, bsum, n2, nblk);

    sage_fill<<<degB, 256, 0, stream>>>(src, dst, off, pos, csr, n_nodes, n_edges);

    sage_aggregate<<<(n2 + 3) / 4, 256, 0, stream>>>(xb, csr, off, deg, hagg, n_nodes);

    int tiles_m = (n_nodes + 127) / 128;         // 391
    int blocks  = tiles_m * (ODIM / 128);        // 3128
    sage_gemm<<<blocks, 256, 0, stream>>>(xb, hagg, Wt, bias, (float*)d_out, n_nodes);
}